// Round 1
// baseline (1453.560 us; speedup 1.0000x reference)
//
#include <hip/hip_runtime.h>

// GruBlock fused kernel, fp32.
// x:(64,64,48,160) -> 1x1 conv (64ch) -> per (b,h) row: biGRU over W=160, H_GRU=32
// out:(64, 64, 48, 160)  [ch 0..31 = forward GRU, ch 32..63 = backward GRU]
//
// One block per sequence n = b*48+h (3072 blocks, 256 threads).
// Phase A: all waves: conv -> s_seq[t][o] (LDS, pad 68 for bank spread, rows 16B-aligned)
// Chunk loop (TC=16, 10 chunks, double-buffered s_pre):
//   wave 0   : GRU scan (lanes 0-31 fwd, 32-63 bwd), whh in 96 VGPRs, h via __shfl
//   waves 1-3: input projection pre[t][d][g] for NEXT chunk (192 threads = 2 dirs x 96 gates)

#define HWSTRIDE 7680   // 48*160
#define TCH 16
#define NCHUNK 10

__global__ __launch_bounds__(256, 2)
void gru_fused(const float* __restrict__ x,
               const float* __restrict__ conv_w,
               const float* __restrict__ conv_b,
               const float* __restrict__ wih_f,
               const float* __restrict__ whh_f,
               const float* __restrict__ bih_f,
               const float* __restrict__ bhh_f,
               const float* __restrict__ wih_b,
               const float* __restrict__ whh_b,
               const float* __restrict__ bih_b,
               const float* __restrict__ bhh_b,
               float* __restrict__ out)
{
    __shared__ float s_seq[160][68];          // 43.5 KB, rows 272B (16B aligned)
    __shared__ float s_pre[2][TCH][2][96];    // 24 KB double-buffered gate pre-activations

    const int n    = blockIdx.x;
    const int b    = n / 48;
    const int h    = n % 48;
    const int tid  = threadIdx.x;
    const int wave = tid >> 6;
    const int lane = tid & 63;

    const float* xbase = x + (size_t)b * (64 * HWSTRIDE) + (size_t)h * 160;

    // ---------------- Phase A: 1x1 conv -> s_seq ----------------
    {
        const int o0 = __builtin_amdgcn_readfirstlane(wave) * 16;  // wave-uniform -> s_loads for conv_w
        for (int tb = 0; tb < 3; ++tb) {
            const int t = tb * 64 + lane;
            if (t < 160) {
                float acc[16];
                #pragma unroll
                for (int i = 0; i < 16; ++i) acc[i] = conv_b[o0 + i];
                const float* xp = xbase + t;
                #pragma unroll 4
                for (int c = 0; c < 64; ++c) {
                    const float xv = xp[(size_t)c * HWSTRIDE];
                    #pragma unroll
                    for (int i = 0; i < 16; ++i)
                        acc[i] += xv * conv_w[(o0 + i) * 64 + c];
                }
                #pragma unroll
                for (int q = 0; q < 4; ++q)
                    *(float4*)&s_seq[t][o0 + q * 4] =
                        make_float4(acc[q*4], acc[q*4+1], acc[q*4+2], acc[q*4+3]);
            }
        }
    }

    // ---------------- per-role weight preloads (registers) ----------------
    // scan wave (wave 0): lanes 0-31 forward (d0=0), lanes 32-63 backward (d0=1)
    const int d0 = lane >> 5;
    const int j  = lane & 31;
    float wr[32], wz[32], wn[32];
    float br = 0.f, bz = 0.f, bn = 0.f, hcur = 0.f;
    float* orow = out + (((size_t)b * 64 + (size_t)(d0 * 32 + j)) * 48 + h) * 160;
    if (wave == 0) {
        const float* whh = d0 ? whh_b : whh_f;
        const float* bhh = d0 ? bhh_b : bhh_f;
        #pragma unroll
        for (int k = 0; k < 32; ++k) {
            wr[k] = whh[(j     ) * 32 + k];
            wz[k] = whh[(j + 32) * 32 + k];
            wn[k] = whh[(j + 64) * 32 + k];
        }
        br = bhh[j]; bz = bhh[j + 32]; bn = bhh[j + 64];
    }
    // pre-projection waves (tid 64..255): thread owns (pd, pg)
    float wreg[64];
    float bg = 0.f;
    int pd = 0, pg = 0;
    if (tid >= 64) {
        const int u = tid - 64;
        pd = u / 96; pg = u % 96;
        const float* wih = pd ? wih_b : wih_f;
        const float* bih = pd ? bih_b : bih_f;
        #pragma unroll
        for (int o = 0; o < 64; ++o) wreg[o] = wih[pg * 64 + o];
        bg = bih[pg];
    }

    __syncthreads();

    // ---------------- prologue: project chunk 0 ----------------
    if (tid >= 64) {
        for (int tq = 0; tq < TCH; ++tq) {
            const int trow = pd ? (159 - tq) : tq;
            const float4* srow = (const float4*)&s_seq[trow][0];
            float acc = bg;
            #pragma unroll
            for (int i4 = 0; i4 < 16; ++i4) {
                const float4 sv = srow[i4];
                acc += sv.x * wreg[i4*4]     + sv.y * wreg[i4*4 + 1]
                     + sv.z * wreg[i4*4 + 2] + sv.w * wreg[i4*4 + 3];
            }
            s_pre[0][tq][pd][pg] = acc;
        }
    }
    __syncthreads();

    // ---------------- main pipelined chunk loop ----------------
    for (int ci = 0; ci < NCHUNK; ++ci) {
        if (wave == 0) {
            // ---- GRU scan over 16 steps of this chunk ----
            const int buf = ci & 1;
            #pragma unroll 1
            for (int gq = 0; gq < 4; ++gq) {
                float hh[4];
                #pragma unroll
                for (int s = 0; s < 4; ++s) {
                    const int tq = gq * 4 + s;
                    const float gir = s_pre[buf][tq][d0][j];
                    const float giz = s_pre[buf][tq][d0][j + 32];
                    const float gin = s_pre[buf][tq][d0][j + 64];
                    float gr = br, gz = bz, gn = bn;
                    #pragma unroll
                    for (int k = 0; k < 32; ++k) {
                        const float hk = __shfl(hcur, k, 32);
                        gr += wr[k] * hk;
                        gz += wz[k] * hk;
                        gn += wn[k] * hk;
                    }
                    const float r = __builtin_amdgcn_rcpf(1.f + __expf(-(gir + gr)));
                    const float z = __builtin_amdgcn_rcpf(1.f + __expf(-(giz + gz)));
                    float ta = gin + r * gn;
                    ta = fminf(fmaxf(ta, -15.f), 15.f);
                    const float e2 = __expf(2.f * ta);
                    const float nn = (e2 - 1.f) * __builtin_amdgcn_rcpf(e2 + 1.f);
                    hcur = (1.f - z) * nn + z * hcur;
                    hh[s] = hcur;
                }
                if (d0 == 0) {
                    *(float4*)&orow[ci * TCH + gq * 4] =
                        make_float4(hh[0], hh[1], hh[2], hh[3]);
                } else {
                    // t_scan = ci*16+gq*4+s  ->  w = 159 - t_scan
                    *(float4*)&orow[156 - ci * TCH - gq * 4] =
                        make_float4(hh[3], hh[2], hh[1], hh[0]);
                }
            }
        } else {
            // ---- project chunk ci+1 into the other buffer ----
            const int cn = ci + 1;
            if (cn < NCHUNK) {
                const int buf = cn & 1;
                for (int tq = 0; tq < TCH; ++tq) {
                    const int tf = cn * TCH + tq;
                    const int trow = pd ? (159 - tf) : tf;
                    const float4* srow = (const float4*)&s_seq[trow][0];
                    float acc = bg;
                    #pragma unroll
                    for (int i4 = 0; i4 < 16; ++i4) {
                        const float4 sv = srow[i4];
                        acc += sv.x * wreg[i4*4]     + sv.y * wreg[i4*4 + 1]
                             + sv.z * wreg[i4*4 + 2] + sv.w * wreg[i4*4 + 3];
                    }
                    s_pre[buf][tq][pd][pg] = acc;
                }
            }
        }
        __syncthreads();
    }
}

extern "C" void kernel_launch(void* const* d_in, const int* in_sizes, int n_in,
                              void* d_out, int out_size, void* d_ws, size_t ws_size,
                              hipStream_t stream) {
    (void)in_sizes; (void)n_in; (void)d_ws; (void)ws_size; (void)out_size;
    gru_fused<<<dim3(3072), dim3(256), 0, stream>>>(
        (const float*)d_in[0],  // x
        (const float*)d_in[1],  // conv_w
        (const float*)d_in[2],  // conv_b
        (const float*)d_in[3],  // wih_f
        (const float*)d_in[4],  // whh_f
        (const float*)d_in[5],  // bih_f
        (const float*)d_in[6],  // bhh_f
        (const float*)d_in[7],  // wih_b
        (const float*)d_in[8],  // whh_b
        (const float*)d_in[9],  // bih_b
        (const float*)d_in[10], // bhh_b
        (float*)d_out);
}

// Round 2
// 316.688 us; speedup vs baseline: 4.5899x; 4.5899x over previous
//
#include <hip/hip_runtime.h>

// GruBlock, round 2: conv folded into projection weights.
// pre_d[t][g] = sum_c W2_d[g][c] * x[c][w(t)] + b2_d[g],
//   W2_d = wih_d @ conv_w  (96x64), b2_d = bih_d + wih_d @ conv_b.
// Kernel 1 (fold_weights): compute W2/b2 into d_ws.
// Kernel 2 (gru_fused2): one block per sequence (3072), 256 threads.
//   scan wave = blockIdx&3 (spreads scan waves across SIMDs), other 3 waves
//   project gates for the next chunk + stage x tiles (double-buffered).
//   h-vector broadcast via s_h[64] in LDS (1 write + 8 b128 reads per step)
//   instead of 32 ds_bpermute shuffles.

#define HWSTRIDE 7680   // 48*160
#define TCH 16
#define NCHUNK 10
#define W2SZ (96*64)

__global__ void fold_weights(const float* __restrict__ conv_w,
                             const float* __restrict__ conv_b,
                             const float* __restrict__ wih_f,
                             const float* __restrict__ bih_f,
                             const float* __restrict__ wih_b,
                             const float* __restrict__ bih_b,
                             float* __restrict__ ws)
{
    const int idx = blockIdx.x * 64 + threadIdx.x;   // [0,768)
    if (idx >= 768) return;
    const int d   = idx / 384;
    const int rem = idx % 384;
    const int g   = rem % 96;
    const int cq  = rem / 96;                        // c quarter
    const float* wih = d ? wih_b : wih_f;
    const float* bih = d ? bih_b : bih_f;
    float* W2 = ws + d * W2SZ;
    for (int c = cq * 16; c < cq * 16 + 16; ++c) {
        float acc = 0.f;
        for (int o = 0; o < 64; ++o)
            acc += wih[g * 64 + o] * conv_w[o * 64 + c];
        W2[g * 64 + c] = acc;
    }
    if (cq == 0) {
        float acc = bih[g];
        for (int o = 0; o < 64; ++o)
            acc += wih[g * 64 + o] * conv_b[o];
        ws[2 * W2SZ + d * 96 + g] = acc;
    }
}

__global__ __launch_bounds__(256, 3)
void gru_fused2(const float* __restrict__ x,
                const float* __restrict__ whh_f,
                const float* __restrict__ bhh_f,
                const float* __restrict__ whh_b,
                const float* __restrict__ bhh_b,
                const float* __restrict__ ws,
                float* __restrict__ out)
{
    __shared__ __align__(16) float x_tile[2][2][64][TCH]; // [buf][dir][c][t] 16 KB
    __shared__ __align__(16) float s_pre[2][TCH][2][96];  // 24 KB
    __shared__ __align__(16) float s_h[64];

    const int n    = blockIdx.x;
    const int b    = n / 48;
    const int h    = n % 48;
    const int tid  = threadIdx.x;
    const int wave = tid >> 6;
    const int lane = tid & 63;
    const int sw   = blockIdx.x & 3;           // which wave scans (SIMD spread)
    const float* xbase = x + (size_t)b * (64 * HWSTRIDE) + (size_t)h * 160;

    if (wave == sw) {
        // ---------------- scan path ----------------
        const int d0 = lane >> 5;
        const int j  = lane & 31;
        const float* whh = d0 ? whh_b : whh_f;
        const float* bhh = d0 ? bhh_b : bhh_f;
        float wr[32], wz[32], wn[32];
        #pragma unroll
        for (int k = 0; k < 32; ++k) {
            wr[k] = whh[(j     ) * 32 + k];
            wz[k] = whh[(j + 32) * 32 + k];
            wn[k] = whh[(j + 64) * 32 + k];
        }
        const float br = bhh[j], bz = bhh[j + 32], bn = bhh[j + 64];
        float hcur = 0.f;
        s_h[lane] = 0.f;
        float* orow = out + (((size_t)b * 64 + (size_t)(d0 * 32 + j)) * 48 + h) * 160;

        __syncthreads();   // matches: stage tile0
        __syncthreads();   // matches: phase -1

        for (int ci = 0; ci < NCHUNK; ++ci) {
            const int buf = ci & 1;
            float hh[16];
            #pragma unroll
            for (int tq = 0; tq < TCH; ++tq) {
                const float gir = s_pre[buf][tq][d0][j];
                const float giz = s_pre[buf][tq][d0][j + 32];
                const float gin = s_pre[buf][tq][d0][j + 64];
                const float4* hv = (const float4*)&s_h[d0 * 32];
                float gr0 = br, gz0 = bz, gn0 = bn;
                float gr1 = 0.f, gz1 = 0.f, gn1 = 0.f;
                #pragma unroll
                for (int k4 = 0; k4 < 8; ++k4) {
                    const float4 h4 = hv[k4];
                    gr0 += wr[k4*4+0] * h4.x; gz0 += wz[k4*4+0] * h4.x; gn0 += wn[k4*4+0] * h4.x;
                    gr1 += wr[k4*4+1] * h4.y; gz1 += wz[k4*4+1] * h4.y; gn1 += wn[k4*4+1] * h4.y;
                    gr0 += wr[k4*4+2] * h4.z; gz0 += wz[k4*4+2] * h4.z; gn0 += wn[k4*4+2] * h4.z;
                    gr1 += wr[k4*4+3] * h4.w; gz1 += wz[k4*4+3] * h4.w; gn1 += wn[k4*4+3] * h4.w;
                }
                const float gr = gr0 + gr1, gz = gz0 + gz1, gn = gn0 + gn1;
                const float r = __builtin_amdgcn_rcpf(1.f + __expf(-(gir + gr)));
                const float z = __builtin_amdgcn_rcpf(1.f + __expf(-(giz + gz)));
                float ta = gin + r * gn;
                ta = fminf(fmaxf(ta, -15.f), 15.f);
                const float e2 = __expf(2.f * ta);
                const float nn = (e2 - 1.f) * __builtin_amdgcn_rcpf(e2 + 1.f);
                hcur = (1.f - z) * nn + z * hcur;
                s_h[lane] = hcur;
                asm volatile("" ::: "memory");   // keep write->next-step-read ordered
                hh[tq] = hcur;
            }
            if (d0 == 0) {
                #pragma unroll
                for (int q = 0; q < 4; ++q)
                    *(float4*)&orow[ci * TCH + q * 4] =
                        make_float4(hh[q*4], hh[q*4+1], hh[q*4+2], hh[q*4+3]);
            } else {
                // t_scan = ci*16 + q*4 + s  ->  w = 159 - t_scan
                #pragma unroll
                for (int q = 0; q < 4; ++q)
                    *(float4*)&orow[156 - ci * TCH - q * 4] =
                        make_float4(hh[q*4+3], hh[q*4+2], hh[q*4+1], hh[q*4]);
            }
            __syncthreads();
        }
    } else {
        // ---------------- projection / staging path ----------------
        const int rel = (wave - sw + 4) & 3;     // 1..3
        const int u   = (rel - 1) * 64 + lane;   // [0,192)
        const int pd  = u / 96;
        const int pg  = u % 96;
        const float* W2 = ws + pd * W2SZ;
        float w2reg[64];
        #pragma unroll
        for (int c4 = 0; c4 < 16; ++c4) {
            const float4 wv = *(const float4*)&W2[pg * 64 + c4 * 4];
            w2reg[c4*4] = wv.x; w2reg[c4*4+1] = wv.y;
            w2reg[c4*4+2] = wv.z; w2reg[c4*4+3] = wv.w;
        }
        const float b2g = ws[2 * W2SZ + pd * 96 + pg];

        const int nrep = (u < 64) ? 2 : 1;       // 256 float4s over 192 threads
        const int c0   = u >> 2,  tq0 = u & 3;
        const int c1   = (u + 192) >> 2, tq1 = (u + 192) & 3;

        // ---- stage tile 0 ----
        {
            float4 f0, f1, g0, g1;
            f0 = *(const float4*)(xbase + (size_t)c0 * HWSTRIDE + tq0 * 4);
            g0 = *(const float4*)(xbase + (size_t)c0 * HWSTRIDE + 144 + tq0 * 4);
            if (nrep == 2) {
                f1 = *(const float4*)(xbase + (size_t)c1 * HWSTRIDE + tq1 * 4);
                g1 = *(const float4*)(xbase + (size_t)c1 * HWSTRIDE + 144 + tq1 * 4);
            }
            *(float4*)&x_tile[0][0][c0][tq0 * 4] = f0;
            *(float4*)&x_tile[0][1][c0][tq0 * 4] = g0;
            if (nrep == 2) {
                *(float4*)&x_tile[0][0][c1][tq1 * 4] = f1;
                *(float4*)&x_tile[0][1][c1][tq1 * 4] = g1;
            }
        }
        __syncthreads();   // stage tile0 done

        // ---- per-phase worker ----
        // phase(-1): project 0, stage 1;  phase ci: project ci+1, stage ci+2
        for (int ph = -1; ph < NCHUNK; ++ph) {
            const int cs = ph + 2;               // chunk to stage
            const int cp = ph + 1;               // chunk to project
            float4 f0, f1, g0, g1;
            if (cs < NCHUNK) {
                const int wF = cs * 16, wB = 144 - cs * 16;
                f0 = *(const float4*)(xbase + (size_t)c0 * HWSTRIDE + wF + tq0 * 4);
                g0 = *(const float4*)(xbase + (size_t)c0 * HWSTRIDE + wB + tq0 * 4);
                if (nrep == 2) {
                    f1 = *(const float4*)(xbase + (size_t)c1 * HWSTRIDE + wF + tq1 * 4);
                    g1 = *(const float4*)(xbase + (size_t)c1 * HWSTRIDE + wB + tq1 * 4);
                }
            }
            if (cp < NCHUNK) {
                const int bufc = cp & 1;
                float acc[16];
                #pragma unroll
                for (int t = 0; t < 16; ++t) acc[t] = b2g;
                const float4* xr = (const float4*)&x_tile[bufc][pd][0][0];
                #pragma unroll
                for (int c = 0; c < 64; ++c) {
                    const float w = w2reg[c];
                    const float4 x0 = xr[c * 4 + 0];
                    const float4 x1 = xr[c * 4 + 1];
                    const float4 x2 = xr[c * 4 + 2];
                    const float4 x3 = xr[c * 4 + 3];
                    acc[0]  += w * x0.x; acc[1]  += w * x0.y; acc[2]  += w * x0.z; acc[3]  += w * x0.w;
                    acc[4]  += w * x1.x; acc[5]  += w * x1.y; acc[6]  += w * x1.z; acc[7]  += w * x1.w;
                    acc[8]  += w * x2.x; acc[9]  += w * x2.y; acc[10] += w * x2.z; acc[11] += w * x2.w;
                    acc[12] += w * x3.x; acc[13] += w * x3.y; acc[14] += w * x3.z; acc[15] += w * x3.w;
                }
                // forward: stored col s is t_scan = cp*16+s
                // backward: stored col s is w = wB+s -> t_scan = cp*16 + (15-s)
                #pragma unroll
                for (int s = 0; s < 16; ++s) {
                    const int row = pd ? (15 - s) : s;
                    s_pre[bufc][row][pd][pg] = acc[s];
                }
            }
            if (cs < NCHUNK) {
                const int bufs = cs & 1;
                *(float4*)&x_tile[bufs][0][c0][tq0 * 4] = f0;
                *(float4*)&x_tile[bufs][1][c0][tq0 * 4] = g0;
                if (nrep == 2) {
                    *(float4*)&x_tile[bufs][0][c1][tq1 * 4] = f1;
                    *(float4*)&x_tile[bufs][1][c1][tq1 * 4] = g1;
                }
            }
            __syncthreads();
        }
    }
}

extern "C" void kernel_launch(void* const* d_in, const int* in_sizes, int n_in,
                              void* d_out, int out_size, void* d_ws, size_t ws_size,
                              hipStream_t stream) {
    (void)in_sizes; (void)n_in; (void)ws_size; (void)out_size;
    float* ws = (float*)d_ws;
    fold_weights<<<dim3(12), dim3(64), 0, stream>>>(
        (const float*)d_in[1],  // conv_w
        (const float*)d_in[2],  // conv_b
        (const float*)d_in[3],  // wih_f
        (const float*)d_in[5],  // bih_f
        (const float*)d_in[7],  // wih_b
        (const float*)d_in[9],  // bih_b
        ws);
    gru_fused2<<<dim3(3072), dim3(256), 0, stream>>>(
        (const float*)d_in[0],  // x
        (const float*)d_in[4],  // whh_f
        (const float*)d_in[6],  // bhh_f
        (const float*)d_in[8],  // whh_b
        (const float*)d_in[10], // bhh_b
        ws,
        (float*)d_out);
}

// Round 3
// 186.936 us; speedup vs baseline: 7.7757x; 1.6941x over previous
//
#include <hip/hip_runtime.h>

// GruBlock round 3: f16-MFMA projection + 2-wave blocks (1 scan + 1 proj).
// pre = W2 @ x  with W2 = wih@conv_w (f16, folded), biases folded to scan side.
// Block = 1 sequence (3072 blocks, 128 threads). Scan wave: fp32 GRU recurrence,
// h broadcast via s_h LDS. Proj wave: stages x (f16) + 24x mfma_f32_16x16x32_f16
// per chunk, D-frags stored to s_pre (f16, padded 100 to avoid 16-way conflicts).

typedef _Float16 f16x8 __attribute__((ext_vector_type(8)));
typedef _Float16 f16x4 __attribute__((ext_vector_type(4)));
typedef float f32x4 __attribute__((ext_vector_type(4)));

#define HWSTRIDE 7680   // 48*160
#define NCHUNK 10

// ws layout (bytes):
//   0:     _Float16 W2[2][96][64]    (24576 B)
//   24576: float    bias[2][4][32]   (1024 B)  kinds: 0=b2r+bhhr, 1=b2z+bhhz, 2=b2n, 3=bhhn
#define WS_BIAS_OFF 24576

__global__ void fold_weights(const float* __restrict__ conv_w,
                             const float* __restrict__ conv_b,
                             const float* __restrict__ wih_f,
                             const float* __restrict__ bih_f,
                             const float* __restrict__ bhh_f,
                             const float* __restrict__ wih_b,
                             const float* __restrict__ bih_b,
                             const float* __restrict__ bhh_b,
                             void* wsv)
{
    _Float16* W2 = (_Float16*)wsv;
    float* bias = (float*)((char*)wsv + WS_BIAS_OFF);
    const int idx = blockIdx.x * 256 + threadIdx.x;
    if (idx < 12288) {
        const int d = idx / 6144, r = idx % 6144, g = r / 64, c = r % 64;
        const float* wih = d ? wih_b : wih_f;
        float acc = 0.f;
        for (int o = 0; o < 64; ++o) acc += wih[g * 64 + o] * conv_w[o * 64 + c];
        W2[idx] = (_Float16)acc;
    } else if (idx < 12288 + 256) {
        const int e = idx - 12288;
        const int d = e >> 7, rr = e & 127, kind = rr >> 5, j = rr & 31;
        const float* wih = d ? wih_b : wih_f;
        const float* bih = d ? bih_b : bih_f;
        const float* bhh = d ? bhh_b : bhh_f;
        float v;
        if (kind == 0 || kind == 1) {
            const int g = j + kind * 32;
            float b2 = bih[g];
            for (int o = 0; o < 64; ++o) b2 += wih[g * 64 + o] * conv_b[o];
            v = b2 + bhh[g];
        } else if (kind == 2) {
            const int g = j + 64;
            float b2 = bih[g];
            for (int o = 0; o < 64; ++o) b2 += wih[g * 64 + o] * conv_b[o];
            v = b2;
        } else {
            v = bhh[j + 64];
        }
        bias[(d * 4 + kind) * 32 + j] = v;
    }
}

__global__ __launch_bounds__(128, 3)
void gru_fused3(const float* __restrict__ x,
                const float* __restrict__ whh_f,
                const float* __restrict__ whh_b,
                const void* __restrict__ wsv,
                float* __restrict__ out)
{
    __shared__ __align__(16) _Float16 xt[2][2][64][16];     // 8 KB  [buf][dir][c][t]
    __shared__ __align__(16) _Float16 s_pre[2][16][2][100]; // 12.5 KB (pad 100 vs 96)
    __shared__ __align__(16) float s_h[64];

    const int n    = blockIdx.x;
    const int b    = n / 48;
    const int h    = n % 48;
    const int lane = threadIdx.x & 63;
    const int wave = threadIdx.x >> 6;
    const int sw   = blockIdx.x & 1;       // scan-wave index (spread across SIMDs)
    const float* xbase = x + (size_t)b * (64 * HWSTRIDE) + (size_t)h * 160;

    if (wave == sw) {
        // ================= scan wave =================
        const int d0 = lane >> 5, j = lane & 31;
        const float* whh = d0 ? whh_b : whh_f;
        float w[96];
        #pragma unroll
        for (int g3 = 0; g3 < 3; ++g3)
            #pragma unroll
            for (int k4 = 0; k4 < 8; ++k4) {
                const float4 wv = *(const float4*)&whh[(j + 32 * g3) * 32 + k4 * 4];
                w[g3 * 32 + k4 * 4 + 0] = wv.x; w[g3 * 32 + k4 * 4 + 1] = wv.y;
                w[g3 * 32 + k4 * 4 + 2] = wv.z; w[g3 * 32 + k4 * 4 + 3] = wv.w;
            }
        const float* bias = (const float*)((const char*)wsv + WS_BIAS_OFF);
        const float bc_r = bias[(d0 * 4 + 0) * 32 + j];
        const float bc_z = bias[(d0 * 4 + 1) * 32 + j];
        const float b2n  = bias[(d0 * 4 + 2) * 32 + j];
        const float bhn  = bias[(d0 * 4 + 3) * 32 + j];
        float* orow = out + (((size_t)b * 64 + (size_t)(d0 * 32 + j)) * 48 + h) * 160;

        s_h[lane] = 0.f;
        float hcur = 0.f;
        __syncthreads();           // prologue: s_pre[0] ready

        for (int ci = 0; ci < NCHUNK; ++ci) {
            const int buf = ci & 1;
            float hh[16];
            #pragma unroll
            for (int tq = 0; tq < 16; ++tq) {
                const float pr = (float)s_pre[buf][tq][d0][j];
                const float pz = (float)s_pre[buf][tq][d0][j + 32];
                const float pn = (float)s_pre[buf][tq][d0][j + 64];
                float4 hq[8];
                #pragma unroll
                for (int q = 0; q < 8; ++q) hq[q] = ((const float4*)&s_h[d0 * 32])[q];
                const float* hv = (const float*)hq;
                float ar = bc_r, az = bc_z, an = bhn;
                float ar2 = 0.f, az2 = 0.f, an2 = 0.f;
                #pragma unroll
                for (int k = 0; k < 32; k += 2) {
                    const float h0 = hv[k], h1 = hv[k + 1];
                    ar  = fmaf(w[k],      h0, ar );
                    az  = fmaf(w[32 + k], h0, az );
                    an  = fmaf(w[64 + k], h0, an );
                    ar2 = fmaf(w[k + 1],      h1, ar2);
                    az2 = fmaf(w[33 + k],     h1, az2);
                    an2 = fmaf(w[65 + k],     h1, an2);
                }
                const float gr = (ar + ar2) + pr;
                const float gz = (az + az2) + pz;
                const float gn = an + an2;
                const float r = __builtin_amdgcn_rcpf(1.f + __expf(-gr));
                const float z = __builtin_amdgcn_rcpf(1.f + __expf(-gz));
                float ta = (pn + b2n) + r * gn;
                ta = fminf(fmaxf(ta, -15.f), 15.f);
                const float e2 = __expf(2.f * ta);
                const float nn = (e2 - 1.f) * __builtin_amdgcn_rcpf(e2 + 1.f);
                hcur = (1.f - z) * nn + z * hcur;
                s_h[lane] = hcur;
                asm volatile("" ::: "memory");
                hh[tq] = hcur;
            }
            if (d0 == 0) {
                #pragma unroll
                for (int q = 0; q < 4; ++q)
                    *(float4*)&orow[ci * 16 + q * 4] =
                        make_float4(hh[q*4], hh[q*4+1], hh[q*4+2], hh[q*4+3]);
            } else {
                const int base = 144 - ci * 16;
                #pragma unroll
                for (int q = 0; q < 4; ++q)
                    *(float4*)&orow[base + q * 4] =
                        make_float4(hh[15-q*4], hh[14-q*4], hh[13-q*4], hh[12-q*4]);
            }
            __syncthreads();
        }
    } else {
        // ================= projection wave =================
        const _Float16* W2 = (const _Float16*)wsv;
        const int t  = lane & 15;
        const int g8 = (lane >> 4) * 8;   // k-slice base (8 elems)
        const int g4 = (lane >> 4) * 4;   // D-frag row base
        // A-fragments, persistent: [dir][gtile][ktile]
        f16x8 A[2][6][2];
        #pragma unroll
        for (int d = 0; d < 2; ++d)
            #pragma unroll
            for (int gt = 0; gt < 6; ++gt)
                #pragma unroll
                for (int kt = 0; kt < 2; ++kt)
                    A[d][gt][kt] = *(const f16x8*)&W2[(d * 96 + gt * 16 + t) * 64 + kt * 32 + g8];

        const int sc = lane >> 2, stq = lane & 3;  // staging: c = sc + 16k, tq = stq

        // ---- helpers as lambdas ----
        auto stage_dir = [&](int cc, int d, float4* v, bool issue) {
            const int w0 = d ? (144 - cc * 16) : (cc * 16);
            if (issue) {
                #pragma unroll
                for (int k = 0; k < 4; ++k)
                    v[k] = *(const float4*)(xbase + (size_t)(sc + 16 * k) * HWSTRIDE + w0 + stq * 4);
            } else {
                #pragma unroll
                for (int k = 0; k < 4; ++k) {
                    f16x4 p;
                    p[0] = (_Float16)v[k].x; p[1] = (_Float16)v[k].y;
                    p[2] = (_Float16)v[k].z; p[3] = (_Float16)v[k].w;
                    *(f16x4*)&xt[cc & 1][d][sc + 16 * k][stq * 4] = p;
                }
            }
        };
        auto project_dir = [&](int cn, int d) {
            const int buf = cn & 1;
            const _Float16* xr = &xt[buf][d][0][0];
            f16x8 bf0, bf1;
            #pragma unroll
            for (int e = 0; e < 8; ++e) {
                bf0[e] = xr[(g8 + e) * 16 + t];
                bf1[e] = xr[(32 + g8 + e) * 16 + t];
            }
            const int row = d ? (15 - t) : t;
            #pragma unroll
            for (int gt = 0; gt < 6; ++gt) {
                f32x4 acc = {0.f, 0.f, 0.f, 0.f};
                acc = __builtin_amdgcn_mfma_f32_16x16x32_f16(A[d][gt][0], bf0, acc, 0, 0, 0);
                acc = __builtin_amdgcn_mfma_f32_16x16x32_f16(A[d][gt][1], bf1, acc, 0, 0, 0);
                f16x4 o;
                o[0] = (_Float16)acc[0]; o[1] = (_Float16)acc[1];
                o[2] = (_Float16)acc[2]; o[3] = (_Float16)acc[3];
                *(f16x4*)&s_pre[buf][row][d][gt * 16 + g4] = o;
            }
        };

        // ---- prologue: stage chunks 0,1; project chunk 0 ----
        {
            float4 v[4];
            stage_dir(0, 0, v, true);  stage_dir(0, 0, v, false);
            stage_dir(0, 1, v, true);  stage_dir(0, 1, v, false);
            stage_dir(1, 0, v, true);  stage_dir(1, 0, v, false);
            stage_dir(1, 1, v, true);  stage_dir(1, 1, v, false);
            project_dir(0, 0);
            project_dir(0, 1);
        }
        __syncthreads();

        // ---- main loop: iter ci projects cn=ci+1, stages cs=ci+2 ----
        for (int ci = 0; ci < NCHUNK; ++ci) {
            const int cn = ci + 1, cs = ci + 2;
            float4 va[4], vb[4];
            if (cs < NCHUNK) stage_dir(cs, 0, va, true);
            if (cn < NCHUNK) project_dir(cn, 0);
            if (cs < NCHUNK) { stage_dir(cs, 0, va, false); stage_dir(cs, 1, vb, true); }
            if (cn < NCHUNK) project_dir(cn, 1);
            if (cs < NCHUNK) stage_dir(cs, 1, vb, false);
            __syncthreads();
        }
    }
}

extern "C" void kernel_launch(void* const* d_in, const int* in_sizes, int n_in,
                              void* d_out, int out_size, void* d_ws, size_t ws_size,
                              hipStream_t stream) {
    (void)in_sizes; (void)n_in; (void)ws_size; (void)out_size;
    fold_weights<<<dim3(49), dim3(256), 0, stream>>>(
        (const float*)d_in[1],  // conv_w
        (const float*)d_in[2],  // conv_b
        (const float*)d_in[3],  // wih_f
        (const float*)d_in[5],  // bih_f
        (const float*)d_in[6],  // bhh_f
        (const float*)d_in[7],  // wih_b
        (const float*)d_in[9],  // bih_b
        (const float*)d_in[10], // bhh_b
        d_ws);
    gru_fused3<<<dim3(3072), dim3(128), 0, stream>>>(
        (const float*)d_in[0],  // x
        (const float*)d_in[4],  // whh_f
        (const float*)d_in[8],  // whh_b
        d_ws,
        (float*)d_out);
}